// Round 1
// baseline (182.717 us; speedup 1.0000x reference)
//
#include <hip/hip_runtime.h>

#define BETA   0.1f
#define MARGIN 0.1f
#define EPSF   1e-6f
#define KNEG   4
#define NBINS  256

__device__ __forceinline__ float wave_sum(float v) {
    #pragma unroll
    for (int off = 32; off >= 1; off >>= 1)
        v += __shfl_xor(v, off, 64);
    return v;
}

// One 64-lane wave per pair-group: lane l holds float4 l of each 256-float row.
// Row loads are 1KB coalesced wave transactions; p-row reused for all 5 energies.
__global__ __launch_bounds__(256) void cone_main(
    const float* __restrict__ proto,
    const int*   __restrict__ pairs,
    const int*   __restrict__ negc,
    float*       __restrict__ bins,   // [0,NBINS): pos partials, [NBINS,2*NBINS): neg
    int P)
{
    const int lane = threadIdx.x & 63;
    const int wid  = threadIdx.x >> 6;
    const int pair = blockIdx.x * 4 + wid;

    float pos_e = 0.f, neg_e = 0.f;
    if (pair < P) {
        const int pi = pairs[2 * pair];
        int idx[5];
        idx[0] = pairs[2 * pair + 1];
        #pragma unroll
        for (int k = 0; k < KNEG; ++k) idx[1 + k] = negc[4 * pair + k];

        // Issue all 6 row loads up-front (memory-level parallelism).
        float4 p = ((const float4*)(proto + (size_t)pi * 256))[lane];
        float4 cv[5];
        #pragma unroll
        for (int j = 0; j < 5; ++j)
            cv[j] = ((const float4*)(proto + (size_t)idx[j] * 256))[lane];

        float p2     = wave_sum(p.x*p.x + p.y*p.y + p.z*p.z + p.w*p.w);
        float norm_p = sqrtf(p2);
        float apert  = asinf(fminf(fmaxf(BETA / (norm_p + EPSF), 0.f), 1.f - EPSF));

        #pragma unroll
        for (int j = 0; j < 5; ++j) {
            float4 c = cv[j];
            float dx = c.x - p.x, dy = c.y - p.y, dz = c.z - p.z, dw = c.w - p.w;
            float c2 = wave_sum(c.x*c.x + c.y*c.y + c.z*c.z + c.w*c.w);
            float d2 = wave_sum(dx*dx + dy*dy + dz*dz + dw*dw);
            // Matches reference numerics: num = |c|^2 - |p|^2 - |c-p|^2
            float num    = c2 - p2 - d2;
            float denom  = 2.f * norm_p * sqrtf(d2) + EPSF;
            float cosang = fminf(fmaxf(num / denom, -1.f + EPSF), 1.f - EPSF);
            float e      = fmaxf(acosf(cosang) - apert, 0.f);
            if (j == 0) pos_e = e;
            else        neg_e += fmaxf(MARGIN - e, 0.f);
        }
    }

    __shared__ float sp[4], sn[4];
    if (lane == 0) { sp[wid] = pos_e; sn[wid] = neg_e; }
    __syncthreads();
    if (threadIdx.x == 0) {
        float ps = sp[0] + sp[1] + sp[2] + sp[3];
        float ns = sn[0] + sn[1] + sn[2] + sn[3];
        const int b = blockIdx.x & (NBINS - 1);   // spread atomics over 256 bins
        atomicAdd(&bins[b],         ps);
        atomicAdd(&bins[NBINS + b], ns);
    }
}

__global__ __launch_bounds__(256) void cone_zero(float* __restrict__ bins) {
    bins[threadIdx.x] = 0.f;
    bins[NBINS + threadIdx.x] = 0.f;
}

__global__ __launch_bounds__(256) void cone_final(
    const float* __restrict__ bins, float* __restrict__ out, int P)
{
    const int t = threadIdx.x, lane = t & 63, wid = t >> 6;
    float ps = wave_sum(bins[t]);
    float ns = wave_sum(bins[NBINS + t]);
    __shared__ float sp[4], sn[4];
    if (lane == 0) { sp[wid] = ps; sn[wid] = ns; }
    __syncthreads();
    if (t == 0) {
        float tp = sp[0] + sp[1] + sp[2] + sp[3];
        float tn = sn[0] + sn[1] + sn[2] + sn[3];
        float fP = (float)P;
        out[0] = (tp / fP + tn / (fP * (float)KNEG)) * 0.5f;
    }
}

extern "C" void kernel_launch(void* const* d_in, const int* in_sizes, int n_in,
                              void* d_out, int out_size, void* d_ws, size_t ws_size,
                              hipStream_t stream) {
    const float* proto = (const float*)d_in[0];
    const int*   pairs = (const int*)d_in[1];
    const int*   negc  = (const int*)d_in[2];
    float*       bins  = (float*)d_ws;          // 2*NBINS floats = 2 KB scratch
    const int P = in_sizes[1] / 2;

    cone_zero<<<1, NBINS, 0, stream>>>(bins);
    cone_main<<<(P + 3) / 4, 256, 0, stream>>>(proto, pairs, negc, bins, P);
    cone_final<<<1, 256, 0, stream>>>(bins, (float*)d_out, P);
}

// Round 2
// 180.065 us; speedup vs baseline: 1.0147x; 1.0147x over previous
//
#include <hip/hip_runtime.h>

#define BETA   0.1f
#define MARGIN 0.1f
#define EPSF   1e-6f
#define KNEG   4

// Reduce over a 16-lane group (4 groups per wave reduce concurrently).
__device__ __forceinline__ float gsum16(float v) {
    #pragma unroll
    for (int off = 8; off >= 1; off >>= 1)
        v += __shfl_xor(v, off, 64);
    return v;
}

__device__ __forceinline__ float wave_sum(float v) {
    #pragma unroll
    for (int off = 32; off >= 1; off >>= 1)
        v += __shfl_xor(v, off, 64);
    return v;
}

__device__ __forceinline__ float dot4(float4 a, float4 b) {
    return a.x*b.x + a.y*b.y + a.z*b.z + a.w*b.w;
}

// 4 pairs per 64-lane wave: 16 lanes/pair, 16 floats/lane. Wave-level costs
// (shuffle reductions, acosf/asinf, scalar tail) amortized over 4 pairs.
__global__ __launch_bounds__(256) void cone_main(
    const float* __restrict__ proto,
    const int*   __restrict__ pairs,
    const int*   __restrict__ negc,
    float*       __restrict__ part,   // [2*gridDim]: interleaved pos/neg partials
    int P)
{
    const int lane = threadIdx.x & 63;
    const int wid  = threadIdx.x >> 6;
    const int sub  = lane >> 4;       // which pair within the wave
    const int sl   = lane & 15;       // lane within the 16-lane group
    const int pair = (blockIdx.x * 4 + wid) * 4 + sub;

    float pos_e = 0.f, neg_e = 0.f;
    if (pair < P) {
        const int pi = pairs[2 * pair];
        int idx[5];
        idx[0] = pairs[2 * pair + 1];
        #pragma unroll
        for (int k = 0; k < KNEG; ++k) idx[1 + k] = negc[4 * pair + k];

        // Issue all 24 row loads up-front (memory-level parallelism).
        const float4* prow = (const float4*)(proto + (size_t)pi * 256);
        float4 pv[4];
        #pragma unroll
        for (int r = 0; r < 4; ++r) pv[r] = prow[sl + 16 * r];

        float4 cv[5][4];
        #pragma unroll
        for (int j = 0; j < 5; ++j) {
            const float4* crow = (const float4*)(proto + (size_t)idx[j] * 256);
            #pragma unroll
            for (int r = 0; r < 4; ++r) cv[j][r] = crow[sl + 16 * r];
        }

        float pp = 0.f;
        #pragma unroll
        for (int r = 0; r < 4; ++r) pp += dot4(pv[r], pv[r]);
        float p2     = gsum16(pp);
        float norm_p = sqrtf(p2);
        float apert  = asinf(fminf(fmaxf(BETA / (norm_p + EPSF), 0.f), 1.f - EPSF));

        #pragma unroll
        for (int j = 0; j < 5; ++j) {
            float cc = 0.f, dd = 0.f;
            #pragma unroll
            for (int r = 0; r < 4; ++r) {
                float4 c = cv[j][r], p = pv[r];
                cc += dot4(c, c);
                float dx = c.x - p.x, dy = c.y - p.y, dz = c.z - p.z, dw = c.w - p.w;
                dd += dx*dx + dy*dy + dz*dz + dw*dw;
            }
            float c2 = gsum16(cc);
            float d2 = gsum16(dd);
            // Matches reference numerics: num = |c|^2 - |p|^2 - |c-p|^2
            float num    = c2 - p2 - d2;
            float denom  = 2.f * norm_p * sqrtf(d2) + EPSF;
            float cosang = fminf(fmaxf(num / denom, -1.f + EPSF), 1.f - EPSF);
            float e      = fmaxf(acosf(cosang) - apert, 0.f);
            if (j == 0) pos_e = e;
            else        neg_e += fmaxf(MARGIN - e, 0.f);
        }
    }

    __shared__ float sp[16], sn[16];
    if (sl == 0) { sp[wid * 4 + sub] = pos_e; sn[wid * 4 + sub] = neg_e; }
    __syncthreads();
    if (threadIdx.x == 0) {
        float ps = 0.f, ns = 0.f;
        #pragma unroll
        for (int i = 0; i < 16; ++i) { ps += sp[i]; ns += sn[i]; }
        part[2 * blockIdx.x]     = ps;   // unconditional write -> no zeroing kernel
        part[2 * blockIdx.x + 1] = ns;
    }
}

__global__ __launch_bounds__(1024) void cone_final(
    const float* __restrict__ part, float* __restrict__ out, int nblocks, int P)
{
    float ps = 0.f, ns = 0.f;
    for (int i = threadIdx.x; i < nblocks; i += 1024) {
        ps += part[2 * i];
        ns += part[2 * i + 1];
    }
    ps = wave_sum(ps);
    ns = wave_sum(ns);
    const int lane = threadIdx.x & 63, wid = threadIdx.x >> 6;
    __shared__ float sp[16], sn[16];
    if (lane == 0) { sp[wid] = ps; sn[wid] = ns; }
    __syncthreads();
    if (threadIdx.x == 0) {
        float tp = 0.f, tn = 0.f;
        #pragma unroll
        for (int i = 0; i < 16; ++i) { tp += sp[i]; tn += sn[i]; }
        float fP = (float)P;
        out[0] = (tp / fP + tn / (fP * (float)KNEG)) * 0.5f;
    }
}

extern "C" void kernel_launch(void* const* d_in, const int* in_sizes, int n_in,
                              void* d_out, int out_size, void* d_ws, size_t ws_size,
                              hipStream_t stream) {
    const float* proto = (const float*)d_in[0];
    const int*   pairs = (const int*)d_in[1];
    const int*   negc  = (const int*)d_in[2];
    float*       part  = (float*)d_ws;
    const int P = in_sizes[1] / 2;
    const int nblocks = (P + 15) / 16;     // 16 pairs per block (4 waves x 4 pairs)

    cone_main<<<nblocks, 256, 0, stream>>>(proto, pairs, negc, part, P);
    cone_final<<<1, 1024, 0, stream>>>(part, (float*)d_out, nblocks, P);
}